// Round 7
// baseline (136.621 us; speedup 1.0000x reference)
//
#include <hip/hip_runtime.h>
#include <hip/hip_bf16.h>

#define B_ 1024
#define IN_ 512
#define OUT_ 512
#define BTILE 64
#define OTILE 32
#define ITILE 16
#define KSPLIT 8
#define KCHUNK (IN_ / KSPLIT)          // 64 i's per block
#define NCHUNKS (KCHUNK / ITILE)       // 4 staging chunks
#define P4STRIDE 128  // 32 o * 4 words; b128 writes start 4*pol -> even 8-phase (free); reads 2-way (free)
#define P2STRIDE 64   // 32 o * 2 words; reads conflict-free; b64 writes 4-phase minimum (free)
#define XSTRIDE 68    // BTILE + 4 pad; 68 % 32 == 4 -> staging writes exactly 2-way (free)

__device__ __forceinline__ float fast_exp2(float x) {
#if __has_builtin(__builtin_amdgcn_exp2f)
    return __builtin_amdgcn_exp2f(x);
#else
    return __exp2f(x);
#endif
}
__device__ __forceinline__ float fast_log2(float x) {
#if __has_builtin(__builtin_amdgcn_logf)
    return __builtin_amdgcn_logf(x);   // v_log_f32 = log2
#else
    return __log2f(x);
#endif
}
__device__ __forceinline__ float fast_cos_rev(float x) {  // cos(2*pi*x), x in revolutions
#if __has_builtin(__builtin_amdgcn_cosf)
    return __builtin_amdgcn_cosf(x);   // v_cos_f32 valid domain +-256 revs; |x| <= ~9 here
#else
    return __cosf(x * 6.2831853071795864f);
#endif
}
__device__ __forceinline__ float fast_rcp(float x) {
#if __has_builtin(__builtin_amdgcn_rcpf)
    return __builtin_amdgcn_rcpf(x);
#else
    return 1.0f / x;
#endif
}

__global__ __launch_bounds__(256, 8) void chirplet_kernel(
    const float* __restrict__ x,
    const float* __restrict__ W,
    const float* __restrict__ Wc,
    const float* __restrict__ S,
    const float* __restrict__ T,
    const float* __restrict__ F,
    const float* __restrict__ bias,
    float* __restrict__ out)
{
    // p split: float4 {a, b', c2, d2} + float2 {lw, w}; 32 o per tile.
    __shared__ __align__(16) float p4_lds[ITILE * P4STRIDE];  // 8 KB
    __shared__ __align__(16) float p2_lds[ITILE * P2STRIDE];  // 4 KB
    __shared__ __align__(16) float x_lds[ITILE * XSTRIDE];    // 4.25 KB  [i][b]
    __shared__ __align__(16) float s_lds[ITILE * XSTRIDE];    // 4.25 KB  silu(x)

    const int tid = threadIdx.x;
    const int o0 = blockIdx.x * OTILE;
    const int b0 = blockIdx.y * BTILE;
    const int k0 = blockIdx.z * KCHUNK;

    // compute mapping: thread = (o pair {oc, oc+16}, 4 consecutive b)
    const int oc = tid & 15;        // 0..15
    const int bq = tid >> 4;        // 0..15 -> b = bq*4 + k

    // x staging: row = tid>>2 (b), col-quad = tid&3; writes exactly 2-way (free)
    const int xrow = tid >> 2;          // 0..63
    const int xq   = tid & 3;           // 0..3

    // p staging: 512 (o,i) per chunk, 2 per thread: (pol, pi) and (pol, pi+8)
    const int pol = tid & 31;           // o 0..31
    const int pi  = tid >> 5;           // i 0..7

    const float LOG2E = 1.4426950408889634f;
    const float GK    = 0.8493218002880191f;   // sqrt(0.5*log2(e)); exp(-0.5*u^2)=exp2(-(GK*u)^2)

    float acc[2][4] = {{0.f,0.f,0.f,0.f},{0.f,0.f,0.f,0.f}};

    for (int c = 0; c < NCHUNKS; ++c) {
        const int ib = k0 + c * ITILE;

        // ---- stage x tile (64 b x 16 i): coalesced load, silu, transpose to [i][b]
        {
            const float4 v = *(const float4*)(x + (size_t)(b0 + xrow) * IN_ + ib + xq * 4);
            const float xf[4] = { v.x, v.y, v.z, v.w };
            #pragma unroll
            for (int j = 0; j < 4; ++j) {
                const int col = xq * 4 + j;
                float xv  = xf[j];
                float sig = fast_rcp(1.0f + fast_exp2(-xv * LOG2E));
                x_lds[col * XSTRIDE + xrow] = xv;
                s_lds[col * XSTRIDE + xrow] = xv * sig;
            }
        }

        // ---- stage params (32 o x 16 i), 2 per thread; fold coefficients.
        // sign(Wc) -> cos phase (+0.5 rev); |Wc| -> exp2 offset lw = log2|Wc|.
        #pragma unroll
        for (int h = 0; h < 2; ++h) {
            const int ii = pi + h * 8;
            const size_t go = (size_t)(o0 + pol) * IN_ + ib + ii;
            const float s  = S[go];
            const float t  = T[go];
            const float f  = F[go];
            const float w  = W[go];
            const float wc = Wc[go];
            const float rs = fast_rcp(s);
            const float a  = f * rs;                       // revolutions per x
            float4 p0; float2 p1;
            p0.x = a;
            p0.y = -a * t + (wc < 0.0f ? 0.5f : 0.0f);     // phase offset + sign(Wc)
            p0.z = rs * GK;
            p0.w = -t * rs * GK;
            p1.x = fast_log2(fabsf(wc));                   // lw
            p1.y = w;
            *(float4*)&p4_lds[ii * P4STRIDE + pol * 4] = p0;
            *(float2*)&p2_lds[ii * P2STRIDE + pol * 2] = p1;
        }
        __syncthreads();

        // ---- compute: each thread 4 b x 2 o over ITILE i's (10 LDS B/elem)
        #pragma unroll 4
        for (int i = 0; i < ITILE; ++i) {
            const float4 ab0 = *(const float4*)&p4_lds[i * P4STRIDE + oc * 4];
            const float4 ab1 = *(const float4*)&p4_lds[i * P4STRIDE + (oc + 16) * 4];
            const float2 lw0 = *(const float2*)&p2_lds[i * P2STRIDE + oc * 2];
            const float2 lw1 = *(const float2*)&p2_lds[i * P2STRIDE + (oc + 16) * 2];
            const float4 xv  = *(const float4*)&x_lds[i * XSTRIDE + bq * 4];
            const float4 svv = *(const float4*)&s_lds[i * XSTRIDE + bq * 4];
            const float xk[4] = { xv.x, xv.y, xv.z, xv.w };
            const float sk[4] = { svv.x, svv.y, svv.z, svv.w };
            const float4 abcd[2] = { ab0, ab1 };
            const float2 lww[2]  = { lw0, lw1 };
            #pragma unroll
            for (int o = 0; o < 2; ++o) {
                #pragma unroll
                for (int k = 0; k < 4; ++k) {
                    float rev = fmaf(abcd[o].x, xk[k], abcd[o].y);   // phase (revs)
                    float co  = fast_cos_rev(rev);                   // +-cos
                    float u   = fmaf(abcd[o].z, xk[k], abcd[o].w);   // GK*(x-t)/s
                    float e   = fast_exp2(fmaf(-u, u, lww[o].x));    // |Wc|*gauss
                    acc[o][k] = fmaf(co, e, acc[o][k]);              // chirplet part
                    acc[o][k] = fmaf(sk[k], lww[o].y, acc[o][k]);    // silu(x)*W
                }
            }
        }
        __syncthreads();
    }

    // ---- epilogue: bias (once, from kslice 0) + fp32 atomic accumulate
    const float badd0 = (blockIdx.z == 0) ? bias[o0 + oc] : 0.0f;
    const float badd1 = (blockIdx.z == 0) ? bias[o0 + oc + 16] : 0.0f;
    #pragma unroll
    for (int k = 0; k < 4; ++k) {
        const int b = b0 + bq * 4 + k;
        float* dst0 = &out[(size_t)b * OUT_ + o0 + oc];
        float* dst1 = &out[(size_t)b * OUT_ + o0 + oc + 16];
#if defined(__HIP_DEVICE_COMPILE__)
        unsafeAtomicAdd(dst0, acc[0][k] + badd0);   // HW global_atomic_add_f32
        unsafeAtomicAdd(dst1, acc[1][k] + badd1);
#else
        atomicAdd(dst0, acc[0][k] + badd0);
        atomicAdd(dst1, acc[1][k] + badd1);
#endif
    }
}

extern "C" void kernel_launch(void* const* d_in, const int* in_sizes, int n_in,
                              void* d_out, int out_size, void* d_ws, size_t ws_size,
                              hipStream_t stream) {
    const float* x    = (const float*)d_in[0];
    const float* W    = (const float*)d_in[1];
    const float* Wc   = (const float*)d_in[2];
    const float* S    = (const float*)d_in[3];
    const float* T    = (const float*)d_in[4];
    const float* F    = (const float*)d_in[5];
    const float* bias = (const float*)d_in[6];
    float* out = (float*)d_out;

    // d_out is poisoned before every launch; atomics need zeroed destination
    hipMemsetAsync(out, 0, (size_t)out_size * sizeof(float), stream);

    dim3 grid(OUT_ / OTILE, B_ / BTILE, KSPLIT);   // 16 x 16 x 8 = 2048 blocks
    chirplet_kernel<<<grid, 256, 0, stream>>>(x, W, Wc, S, T, F, bias, out);
}